// Round 5
// baseline (163.956 us; speedup 1.0000x reference)
//
#include <hip/hip_runtime.h>

// PFNN: 4 branches of 3->32->32->32->1 tanh MLP, N=1M points, fp32 in/out.
// Round 12: revert R11's unroll-2 (spill pathology: WRITE_SIZE 16->108MB,
// scratch ~88B/thread, dur +3us) and instead fill in-order issue bubbles by
// LOOP ROTATION at constant register cost:
//   body(b) = { L1(b); L2(b); issue L3 row-reads (4x ds_read_b128, held in
//   16 VGPR); L0(b+1) [register-only MFMAs + trans epi]; fdot2 tree }.
//   Same-wave LDS ordering makes read-before-overwrite safe; compiler cannot
//   reorder (can't disprove aliasing). L3's lgkm waits + serial dot chain now
//   overlap L0(b+1)'s independent work.
//   - fdot2 as 4-accumulator tree (dep chain 16 -> 4+2), uint4 W3 loads.
//   - kept from R11: float2 bias pairs (1 b64 load per layer-branch).
//   - unchanged: MFMA L0 (hi/lo f16 split), centered-inverse fold (-2 in W),
//     batched-rcp inv4c, HROW=80 b128 A-reads, launch_bounds(256,8).
// Cycle model (R10, holds): trans quarter-rate -> ~66% of VALU pipe; floor
// ~78us at perfect packing; this round targets the 16% packing gap.

#define NPTS 1048576
#define BLOCK 256
#define HROW 80          // bytes per h row in LDS (16B aligned)
#define SCALE 2.8853900817779268f   // 2*log2(e)

// ws layout (bytes):
// 0..16383   : WfH [2][4][2][16][32] f16 (hidden weights, -2*SCALE, permuted)
#define OFF_BSC  16384   // Bsc [2][4][16] float2 (hidden bias pairs, scaled)
#define OFF_W0F  17408   // W0f [4][2][16][32] f16 (L0 hi/lo packed, scaled)
#define OFF_B0P  25600   // B0p [4][16] float2 (L0 bias pairs, scaled)
#define OFF_W3P  26112   // W3p [4][16] u32 (f16 pairs of -2*w3)

using f16   = _Float16;
using f16x8 = __attribute__((ext_vector_type(8))) _Float16;  // MFMA A/B frag
using f32x4 = __attribute__((ext_vector_type(4))) float;     // MFMA C/D frag
using hfx2  = decltype(__builtin_amdgcn_cvt_pkrtz(0.0f, 0.0f)); // __fp16x2

// 4 centered inverses with ONE v_rcp: o_i = 1/(exp2(v_i)+1) - 0.5.
// (h = tanh = -2*o with pre-scaled v; the -2 is folded into next-layer W.)
__device__ __forceinline__ void inv4c(float v0, float v1, float v2, float v3,
                                      float& o0, float& o1, float& o2, float& o3)
{
    float a0 = __builtin_amdgcn_exp2f(v0) + 1.0f;
    float a1 = __builtin_amdgcn_exp2f(v1) + 1.0f;
    float a2 = __builtin_amdgcn_exp2f(v2) + 1.0f;
    float a3 = __builtin_amdgcn_exp2f(v3) + 1.0f;
    float p01 = a0 * a1;
    float p23 = a2 * a3;
    float p   = p01 * p23;
    float r   = __builtin_amdgcn_rcpf(p);
    float r01 = r * p23;            // 1/(a0*a1)
    float r23 = r * p01;            // 1/(a2*a3)
    o0 = __builtin_fmaf(r01, a1, -0.5f);   // 1/a0 - 0.5
    o1 = __builtin_fmaf(r01, a0, -0.5f);   // 1/a1 - 0.5
    o2 = __builtin_fmaf(r23, a3, -0.5f);   // 1/a2 - 0.5
    o3 = __builtin_fmaf(r23, a2, -0.5f);   // 1/a3 - 0.5
}

// per-mt epilogue: inv4c over (c0[r],c1[r],c0[r+1],c1[r+1]) -> 2 packed b32
__device__ __forceinline__ void epi_mt(const f32x4& c0, const f32x4& c1, int mt,
                                       unsigned char* __restrict__ H,
                                       int col, int quad)
{
    #pragma unroll
    for (int r = 0; r < 4; r += 2) {
        int p = mt * 16 + quad * 4 + r;
        float o0, o1, o2, o3;
        inv4c(c0[r], c1[r], c0[r + 1], c1[r + 1], o0, o1, o2, o3);
        union { hfx2 h; unsigned int u; } cv0, cv1;
        cv0.h = __builtin_amdgcn_cvt_pkrtz(o0, o1);
        cv1.h = __builtin_amdgcn_cvt_pkrtz(o2, o3);
        *reinterpret_cast<unsigned int*>(H + p * HROW + 4 * col)       = cv0.u;
        *reinterpret_cast<unsigned int*>(H + (p + 1) * HROW + 4 * col) = cv1.u;
    }
}

// layer 0 for branch b: 3 -> 32 via MFMA on xfrag (fp32-equivalent)
__device__ __forceinline__ void layer0_block(int b, const f16x8 (&xfrag)[4],
                                             const f16* __restrict__ W0f,
                                             const float* __restrict__ B0p,
                                             unsigned char* __restrict__ H,
                                             int col, int quad)
{
    const f16* wb = W0f + (b * 2) * 512;
    f16x8 bf0 = *reinterpret_cast<const f16x8*>(wb + col * 32 + quad * 8);
    f16x8 bf1 = *reinterpret_cast<const f16x8*>(wb + 512 + col * 32 + quad * 8);
    const float2 bp = *reinterpret_cast<const float2*>(B0p + ((b * 16 + col) << 1));
    f32x4 ci0 = {bp.x, bp.x, bp.x, bp.x};   // shared C operand, all mt
    f32x4 ci1 = {bp.y, bp.y, bp.y, bp.y};

    #pragma unroll
    for (int mt = 0; mt < 4; ++mt) {
        f32x4 c0 = __builtin_amdgcn_mfma_f32_16x16x32_f16(xfrag[mt], bf0, ci0, 0, 0, 0);
        f32x4 c1 = __builtin_amdgcn_mfma_f32_16x16x32_f16(xfrag[mt], bf1, ci1, 0, 0, 0);
        epi_mt(c0, c1, mt, H, col, quad);
    }
}

// hidden layer l (0->L1, 1->L2) for branch b: 32 -> 32 via MFMA from H
__device__ __forceinline__ void hidden_block(int l, int b,
                                             const f16* __restrict__ Wf,
                                             const float* __restrict__ Bsc,
                                             unsigned char* __restrict__ H,
                                             int col, int quad)
{
    const f16* wb = Wf + ((l * 4 + b) * 2) * 512;
    f16x8 bf0 = *reinterpret_cast<const f16x8*>(wb + col * 32 + quad * 8);
    f16x8 bf1 = *reinterpret_cast<const f16x8*>(wb + 512 + col * 32 + quad * 8);
    const float2 bp = *reinterpret_cast<const float2*>(
        Bsc + (((l * 4 + b) * 16 + col) << 1));
    f32x4 ci0 = {bp.x, bp.x, bp.x, bp.x};   // shared C operand, all mt
    f32x4 ci1 = {bp.y, bp.y, bp.y, bp.y};

    #pragma unroll
    for (int mt = 0; mt < 4; ++mt) {
        const f16x8 av = *reinterpret_cast<const f16x8*>(
            H + (mt * 16 + col) * HROW + quad * 16);   // 16B aligned
        f32x4 c0 = __builtin_amdgcn_mfma_f32_16x16x32_f16(av, bf0, ci0, 0, 0, 0);
        f32x4 c1 = __builtin_amdgcn_mfma_f32_16x16x32_f16(av, bf1, ci1, 0, 0, 0);
        epi_mt(c0, c1, mt, H, col, quad);
    }
}

// 8-element f16 dot: acc += sum(u[i]*w[i]) via fdot2/fma
__device__ __forceinline__ float dot8(unsigned int ux, unsigned int uy,
                                      unsigned int uz, unsigned int uw,
                                      uint4 w, float acc)
{
#if __has_builtin(__builtin_amdgcn_fdot2)
    union { unsigned int uu; hfx2 hh; } a0, a1, a2, a3, b0, b1, b2, b3;
    a0.uu = ux; a1.uu = uy; a2.uu = uz; a3.uu = uw;
    b0.uu = w.x; b1.uu = w.y; b2.uu = w.z; b3.uu = w.w;
    acc = __builtin_amdgcn_fdot2(a0.hh, b0.hh, acc, false);
    acc = __builtin_amdgcn_fdot2(a1.hh, b1.hh, acc, false);
    acc = __builtin_amdgcn_fdot2(a2.hh, b2.hh, acc, false);
    acc = __builtin_amdgcn_fdot2(a3.hh, b3.hh, acc, false);
#else
    union { unsigned int uu; f16 h[2]; } a[4], bw[4];
    a[0].uu = ux; a[1].uu = uy; a[2].uu = uz; a[3].uu = uw;
    bw[0].uu = w.x; bw[1].uu = w.y; bw[2].uu = w.z; bw[3].uu = w.w;
    #pragma unroll
    for (int q = 0; q < 4; ++q) {
        acc = __builtin_fmaf((float)a[q].h[0], (float)bw[q].h[0], acc);
        acc = __builtin_fmaf((float)a[q].h[1], (float)bw[q].h[1], acc);
    }
#endif
    return acc;
}

__global__ void prep_kernel(const float* __restrict__ W0, const float* __restrict__ b0,
                            const float* __restrict__ W1, const float* __restrict__ b1,
                            const float* __restrict__ W2, const float* __restrict__ b2,
                            const float* __restrict__ W3,
                            unsigned char* __restrict__ ws)
{
    int i = blockIdx.x * 256 + threadIdx.x;
    if (i < 8192) {
        // WfH[l][b][t][n][k] = -2 * SCALE * W_l[b][k][2n+t]  (f16)
        int k = i & 31, n = (i >> 5) & 15, t = (i >> 9) & 1, b = (i >> 10) & 3, l = i >> 12;
        int f = 2 * n + t;
        const float* W = l ? W2 : W1;
        reinterpret_cast<f16*>(ws)[i] = (f16)(-2.0f * SCALE * W[(b * 32 + k) * 32 + f]);
    } else if (i < 8448) {
        // Bsc pairs: [(l*4+b)*16+n] -> (bias_even, bias_odd)
        int j = i - 8192;
        int n = j & 15, t = (j >> 4) & 1, b = (j >> 5) & 3, l = j >> 7;
        const float* bb = l ? b2 : b1;
        reinterpret_cast<float*>(ws + OFF_BSC)[(((l * 4 + b) * 16 + n) << 1) | t]
            = SCALE * bb[b * 32 + 2 * n + t];
    } else if (i < 12544) {
        // W0f[b][t][n][k]: quad q = k>>3, jj = k&7.
        //   q==0, jj<3 : Wh row jj      (pairs with xh -> xh*Wh)
        //   q==0, 3<=jj<6 : Wh row jj-3 (pairs with xl -> xl*Wh)
        //   q==1, jj<3 : Wl row jj      (pairs with xh -> xh*Wl)
        //   else 0
        int j = i - 8448;
        int k = j & 31, n = (j >> 5) & 15, t = (j >> 9) & 1, b = (j >> 10) & 3;
        int f = 2 * n + t;
        int q = k >> 3, jj = k & 7;
        int row = -1; bool lo = false;
        if (q == 0 && jj < 6)      row = (jj < 3) ? jj : jj - 3;
        else if (q == 1 && jj < 3) { row = jj; lo = true; }
        f16 outv = (f16)0.0f;
        if (row >= 0) {
            float w  = SCALE * W0[(b * 3 + row) * 32 + f];
            f16   wh = (f16)w;
            outv = lo ? (f16)(w - (float)wh) : wh;
        }
        reinterpret_cast<f16*>(ws + OFF_W0F)[((b * 2 + t) * 16 + n) * 32 + k] = outv;
    } else if (i < 12672) {
        // B0p pairs: [b*16+n] -> (bias_even, bias_odd)
        int j = i - 12544;
        int n = j & 15, t = (j >> 4) & 1, b = j >> 5;
        reinterpret_cast<float*>(ws + OFF_B0P)[(((b) * 16 + n) << 1) | t]
            = SCALE * b0[b * 32 + 2 * n + t];
    } else if (i < 12736) {
        int j = i - 12672;              // j = b*16 + pair
        union { hfx2 h; unsigned int u; } cv;
        cv.h = __builtin_amdgcn_cvt_pkrtz(-2.0f * W3[2 * j], -2.0f * W3[2 * j + 1]);
        reinterpret_cast<unsigned int*>(ws + OFF_W3P)[j] = cv.u;
    }
}

__global__ __launch_bounds__(BLOCK, 8) void pfnn_kernel(
    const float* __restrict__ x, const unsigned char* __restrict__ ws,
    const float* __restrict__ b3,
    float* __restrict__ out)
{
    __shared__ __align__(16) unsigned char Hl[4][64 * HROW]; // per-wave h tile

    const f16*   Wf  = reinterpret_cast<const f16*>(ws);
    const float* Bsc = reinterpret_cast<const float*>(ws + OFF_BSC);
    const f16*   W0f = reinterpret_cast<const f16*>(ws + OFF_W0F);
    const float* B0p = reinterpret_cast<const float*>(ws + OFF_B0P);
    const unsigned int* W3p = reinterpret_cast<const unsigned int*>(ws + OFF_W3P);

    const int t    = threadIdx.x;
    const int lane = t & 63;
    const int wv   = t >> 6;
    const int col  = lane & 15;
    const int quad = lane >> 4;
    unsigned char* __restrict__ H = &Hl[wv][0];

    const int n0 = blockIdx.x * BLOCK + t;
    const float x0 = x[3 * n0 + 0];
    const float x1 = x[3 * n0 + 1];
    const float x2 = x[3 * n0 + 2];

    // ---- build L0 A-frags once: hi/lo f16 split of x, gathered per m-tile ----
    // d0=(xh0,xh1) d1=(xh2,xl0) d2=(xl1,xl2); frag = [d0,d1,d2,0] for ALL quads.
    f16x8 xfrag[4];
    {
        union { hfx2 h; int u; } q0_, q1_, q2_;
        q0_.h = __builtin_amdgcn_cvt_pkrtz(x0, x1);          // RTZ hi parts
        float r0 = x0 - (float)q0_.h[0];
        float r1 = x1 - (float)q0_.h[1];
        q1_.h = __builtin_amdgcn_cvt_pkrtz(x2, r0);
        float r2 = x2 - (float)q1_.h[0];
        q2_.h = __builtin_amdgcn_cvt_pkrtz(r1, r2);
        int d0 = q0_.u, d1 = q1_.u, d2 = q2_.u;
        #pragma unroll
        for (int mt = 0; mt < 4; ++mt) {
            int addr = 4 * (mt * 16 + col);                  // byte addr = lane*4
            union { int i[4]; f16x8 f; } u;
            u.i[0] = __builtin_amdgcn_ds_bpermute(addr, d0);
            u.i[1] = __builtin_amdgcn_ds_bpermute(addr, d1);
            u.i[2] = __builtin_amdgcn_ds_bpermute(addr, d2);
            u.i[3] = 0;
            xfrag[mt] = u.f;
        }
    }

    float res[4];
    const unsigned char* __restrict__ row = H + lane * HROW;

    layer0_block(0, xfrag, W0f, B0p, H, col, quad);   // prologue

    #pragma unroll 1
    for (int b = 0; b < 3; ++b) {
        hidden_block(0, b, Wf, Bsc, H, col, quad);
        hidden_block(1, b, Wf, Bsc, H, col, quad);

        // L3 row reads: ISSUE before L0(b+1)'s epi overwrites H (same-wave
        // LDS ordering guarantees we read branch b's h2). Held in 16 VGPRs.
        uint4 u0 = *reinterpret_cast<const uint4*>(row);
        uint4 u1 = *reinterpret_cast<const uint4*>(row + 16);
        uint4 u2 = *reinterpret_cast<const uint4*>(row + 32);
        uint4 u3 = *reinterpret_cast<const uint4*>(row + 48);

        // independent work to overlap L3's lgkm waits + dot chain:
        layer0_block(b + 1, xfrag, W0f, B0p, H, col, quad);

        const uint4* wv4 = reinterpret_cast<const uint4*>(W3p + b * 16);
        uint4 w0 = wv4[0], w1 = wv4[1], w2 = wv4[2], w3v = wv4[3];
        float a0 = dot8(u0.x, u0.y, u0.z, u0.w, w0, b3[b]);
        float a1 = dot8(u1.x, u1.y, u1.z, u1.w, w1, 0.0f);
        float a2 = dot8(u2.x, u2.y, u2.z, u2.w, w2, 0.0f);
        float a3 = dot8(u3.x, u3.y, u3.z, u3.w, w3v, 0.0f);
        res[b] = (a0 + a1) + (a2 + a3);
    }

    // tail: branch 3 (no next L0)
    {
        hidden_block(0, 3, Wf, Bsc, H, col, quad);
        hidden_block(1, 3, Wf, Bsc, H, col, quad);
        uint4 u0 = *reinterpret_cast<const uint4*>(row);
        uint4 u1 = *reinterpret_cast<const uint4*>(row + 16);
        uint4 u2 = *reinterpret_cast<const uint4*>(row + 32);
        uint4 u3 = *reinterpret_cast<const uint4*>(row + 48);
        const uint4* wv4 = reinterpret_cast<const uint4*>(W3p + 3 * 16);
        uint4 w0 = wv4[0], w1 = wv4[1], w2 = wv4[2], w3v = wv4[3];
        float a0 = dot8(u0.x, u0.y, u0.z, u0.w, w0, b3[3]);
        float a1 = dot8(u1.x, u1.y, u1.z, u1.w, w1, 0.0f);
        float a2 = dot8(u2.x, u2.y, u2.z, u2.w, w2, 0.0f);
        float a3 = dot8(u3.x, u3.y, u3.z, u3.w, w3v, 0.0f);
        res[3] = (a0 + a1) + (a2 + a3);
    }

    float4 r4 = make_float4(res[0], res[1], res[2], res[3]);
    *reinterpret_cast<float4*>(out + 4 * n0) = r4;
}

extern "C" void kernel_launch(void* const* d_in, const int* in_sizes, int n_in,
                              void* d_out, int out_size, void* d_ws, size_t ws_size,
                              hipStream_t stream) {
    const float* x  = (const float*)d_in[0];
    const float* W0 = (const float*)d_in[1];
    const float* b0 = (const float*)d_in[2];
    const float* W1 = (const float*)d_in[3];
    const float* b1 = (const float*)d_in[4];
    const float* W2 = (const float*)d_in[5];
    const float* b2 = (const float*)d_in[6];
    const float* W3 = (const float*)d_in[7];
    const float* b3 = (const float*)d_in[8];
    float* out = (float*)d_out;
    unsigned char* ws = (unsigned char*)d_ws;

    prep_kernel<<<dim3(50), dim3(256), 0, stream>>>(W0, b0, W1, b1, W2, b2, W3, ws);
    pfnn_kernel<<<dim3(NPTS / BLOCK), dim3(BLOCK), 0, stream>>>(x, ws, b3, out);
}

// Round 7
// 148.041 us; speedup vs baseline: 1.1075x; 1.1075x over previous
//
#include <hip/hip_runtime.h>

// PFNN: 4 branches of 3->32->32->32->1 tanh MLP, N=1M points, fp32 in/out.
// Round 14: R13's hand-written VOP3P asm produced NaN (hazard recognizer
// can't see inside asm consuming v_exp_f32 results / op_sel defaults opaque).
// Same packed-FP32 idea, but COMPILER-NATIVE: f32x2 ext-vector arithmetic +
// __builtin_elementwise_fma lower to v_pk_{add,mul,fma}_f32 on gfx90a+ with
// correct hazards and pair alignment. Bitwise-identical math to scalar inv4c
// -> absmax must stay 0.001953125. Bounded downside: if scalarized, identical
// to the proven R10 stream (93.8us).
//   - packed inv4c: pairs (a0,a2),(a1,a3); 13 scalar VALU -> ~8-9 (2 pk_add,
//     1 pk_mul, 1 mul, swap+mul for R, 2 pk_fma) around 4 exp2 + 1 rcp.
//   - kept: tree dot8 (R12-proven), uint4 W3 loads, float2 bias pairs,
//     MFMA L0 (hi/lo f16 split), centered-inverse fold (-2 in W),
//     HROW=80 b128 A-reads, launch_bounds(256,8), per-wave LDS h tile.

#define NPTS 1048576
#define BLOCK 256
#define HROW 80          // bytes per h row in LDS (16B aligned)
#define SCALE 2.8853900817779268f   // 2*log2(e)

// ws layout (bytes):
// 0..16383   : WfH [2][4][2][16][32] f16 (hidden weights, -2*SCALE, permuted)
#define OFF_BSC  16384   // Bsc [2][4][16] float2 (hidden bias pairs, scaled)
#define OFF_W0F  17408   // W0f [4][2][16][32] f16 (L0 hi/lo packed, scaled)
#define OFF_B0P  25600   // B0p [4][16] float2 (L0 bias pairs, scaled)
#define OFF_W3P  26112   // W3p [4][16] u32 (f16 pairs of -2*w3)

using f16   = _Float16;
using f16x8 = __attribute__((ext_vector_type(8))) _Float16;  // MFMA A/B frag
using f32x4 = __attribute__((ext_vector_type(4))) float;     // MFMA C/D frag
using f32x2 = __attribute__((ext_vector_type(2))) float;     // packed-f32 pair
using hfx2  = decltype(__builtin_amdgcn_cvt_pkrtz(0.0f, 0.0f)); // __fp16x2

// 4 centered inverses with ONE v_rcp: o_i = 1/(exp2(v_i)+1) - 0.5.
// (h = tanh = -2*o with pre-scaled v; the -2 is folded into next-layer W.)
// Packed grouping: x=(a0,a2), y=(a1,a3) keeps every vector op elementwise;
// compiler lowers f32x2 arith to v_pk_*_f32 (gfx90a+ packed-fp32).
__device__ __forceinline__ void inv4c(float v0, float v1, float v2, float v3,
                                      float& o0, float& o1, float& o2, float& o3)
{
    f32x2 x = {__builtin_amdgcn_exp2f(v0), __builtin_amdgcn_exp2f(v2)};
    f32x2 y = {__builtin_amdgcn_exp2f(v1), __builtin_amdgcn_exp2f(v3)};
    const f32x2 one2  = {1.0f, 1.0f};
    const f32x2 negh2 = {-0.5f, -0.5f};
    x = x + one2;                              // (a0, a2)
    y = y + one2;                              // (a1, a3)
    f32x2 P = x * y;                           // (p01, p23)
    float p = P[0] * P[1];
    float r = __builtin_amdgcn_rcpf(p);
    f32x2 rr = {r, r};
    f32x2 Ps = __builtin_shufflevector(P, P, 1, 0);   // (p23, p01)
    f32x2 R  = rr * Ps;                        // (1/p01, 1/p23)
#if __has_builtin(__builtin_elementwise_fma)
    f32x2 o02 = __builtin_elementwise_fma(R, y, negh2);  // (1/a0-.5, 1/a2-.5)
    f32x2 o13 = __builtin_elementwise_fma(R, x, negh2);  // (1/a1-.5, 1/a3-.5)
#else
    f32x2 o02 = {__builtin_fmaf(R[0], y[0], -0.5f), __builtin_fmaf(R[1], y[1], -0.5f)};
    f32x2 o13 = {__builtin_fmaf(R[0], x[0], -0.5f), __builtin_fmaf(R[1], x[1], -0.5f)};
#endif
    o0 = o02[0]; o1 = o13[0]; o2 = o02[1]; o3 = o13[1];
}

// per-mt epilogue: inv4c over (c0[r],c1[r],c0[r+1],c1[r+1]) -> 2 packed b32
__device__ __forceinline__ void epi_mt(const f32x4& c0, const f32x4& c1, int mt,
                                       unsigned char* __restrict__ H,
                                       int col, int quad)
{
    #pragma unroll
    for (int r = 0; r < 4; r += 2) {
        int p = mt * 16 + quad * 4 + r;
        float o0, o1, o2, o3;
        inv4c(c0[r], c1[r], c0[r + 1], c1[r + 1], o0, o1, o2, o3);
        union { hfx2 h; unsigned int u; } cv0, cv1;
        cv0.h = __builtin_amdgcn_cvt_pkrtz(o0, o1);
        cv1.h = __builtin_amdgcn_cvt_pkrtz(o2, o3);
        *reinterpret_cast<unsigned int*>(H + p * HROW + 4 * col)       = cv0.u;
        *reinterpret_cast<unsigned int*>(H + (p + 1) * HROW + 4 * col) = cv1.u;
    }
}

// layer 0 for branch b: 3 -> 32 via MFMA on xfrag (fp32-equivalent)
__device__ __forceinline__ void layer0_block(int b, const f16x8 (&xfrag)[4],
                                             const f16* __restrict__ W0f,
                                             const float* __restrict__ B0p,
                                             unsigned char* __restrict__ H,
                                             int col, int quad)
{
    const f16* wb = W0f + (b * 2) * 512;
    f16x8 bf0 = *reinterpret_cast<const f16x8*>(wb + col * 32 + quad * 8);
    f16x8 bf1 = *reinterpret_cast<const f16x8*>(wb + 512 + col * 32 + quad * 8);
    const float2 bp = *reinterpret_cast<const float2*>(B0p + ((b * 16 + col) << 1));
    f32x4 ci0 = {bp.x, bp.x, bp.x, bp.x};   // shared C operand, all mt
    f32x4 ci1 = {bp.y, bp.y, bp.y, bp.y};

    #pragma unroll
    for (int mt = 0; mt < 4; ++mt) {
        f32x4 c0 = __builtin_amdgcn_mfma_f32_16x16x32_f16(xfrag[mt], bf0, ci0, 0, 0, 0);
        f32x4 c1 = __builtin_amdgcn_mfma_f32_16x16x32_f16(xfrag[mt], bf1, ci1, 0, 0, 0);
        epi_mt(c0, c1, mt, H, col, quad);
    }
}

// hidden layer l (0->L1, 1->L2) for branch b: 32 -> 32 via MFMA from H
__device__ __forceinline__ void hidden_block(int l, int b,
                                             const f16* __restrict__ Wf,
                                             const float* __restrict__ Bsc,
                                             unsigned char* __restrict__ H,
                                             int col, int quad)
{
    const f16* wb = Wf + ((l * 4 + b) * 2) * 512;
    f16x8 bf0 = *reinterpret_cast<const f16x8*>(wb + col * 32 + quad * 8);
    f16x8 bf1 = *reinterpret_cast<const f16x8*>(wb + 512 + col * 32 + quad * 8);
    const float2 bp = *reinterpret_cast<const float2*>(
        Bsc + (((l * 4 + b) * 16 + col) << 1));
    f32x4 ci0 = {bp.x, bp.x, bp.x, bp.x};   // shared C operand, all mt
    f32x4 ci1 = {bp.y, bp.y, bp.y, bp.y};

    #pragma unroll
    for (int mt = 0; mt < 4; ++mt) {
        const f16x8 av = *reinterpret_cast<const f16x8*>(
            H + (mt * 16 + col) * HROW + quad * 16);   // 16B aligned
        f32x4 c0 = __builtin_amdgcn_mfma_f32_16x16x32_f16(av, bf0, ci0, 0, 0, 0);
        f32x4 c1 = __builtin_amdgcn_mfma_f32_16x16x32_f16(av, bf1, ci1, 0, 0, 0);
        epi_mt(c0, c1, mt, H, col, quad);
    }
}

// 8-element f16 dot: acc += sum(u[i]*w[i]) via fdot2/fma
__device__ __forceinline__ float dot8(unsigned int ux, unsigned int uy,
                                      unsigned int uz, unsigned int uw,
                                      uint4 w, float acc)
{
#if __has_builtin(__builtin_amdgcn_fdot2)
    union { unsigned int uu; hfx2 hh; } a0, a1, a2, a3, b0, b1, b2, b3;
    a0.uu = ux; a1.uu = uy; a2.uu = uz; a3.uu = uw;
    b0.uu = w.x; b1.uu = w.y; b2.uu = w.z; b3.uu = w.w;
    acc = __builtin_amdgcn_fdot2(a0.hh, b0.hh, acc, false);
    acc = __builtin_amdgcn_fdot2(a1.hh, b1.hh, acc, false);
    acc = __builtin_amdgcn_fdot2(a2.hh, b2.hh, acc, false);
    acc = __builtin_amdgcn_fdot2(a3.hh, b3.hh, acc, false);
#else
    union { unsigned int uu; f16 h[2]; } a[4], bw[4];
    a[0].uu = ux; a[1].uu = uy; a[2].uu = uz; a[3].uu = uw;
    bw[0].uu = w.x; bw[1].uu = w.y; bw[2].uu = w.z; bw[3].uu = w.w;
    #pragma unroll
    for (int q = 0; q < 4; ++q) {
        acc = __builtin_fmaf((float)a[q].h[0], (float)bw[q].h[0], acc);
        acc = __builtin_fmaf((float)a[q].h[1], (float)bw[q].h[1], acc);
    }
#endif
    return acc;
}

__global__ void prep_kernel(const float* __restrict__ W0, const float* __restrict__ b0,
                            const float* __restrict__ W1, const float* __restrict__ b1,
                            const float* __restrict__ W2, const float* __restrict__ b2,
                            const float* __restrict__ W3,
                            unsigned char* __restrict__ ws)
{
    int i = blockIdx.x * 256 + threadIdx.x;
    if (i < 8192) {
        // WfH[l][b][t][n][k] = -2 * SCALE * W_l[b][k][2n+t]  (f16)
        int k = i & 31, n = (i >> 5) & 15, t = (i >> 9) & 1, b = (i >> 10) & 3, l = i >> 12;
        int f = 2 * n + t;
        const float* W = l ? W2 : W1;
        reinterpret_cast<f16*>(ws)[i] = (f16)(-2.0f * SCALE * W[(b * 32 + k) * 32 + f]);
    } else if (i < 8448) {
        // Bsc pairs: [(l*4+b)*16+n] -> (bias_even, bias_odd)
        int j = i - 8192;
        int n = j & 15, t = (j >> 4) & 1, b = (j >> 5) & 3, l = j >> 7;
        const float* bb = l ? b2 : b1;
        reinterpret_cast<float*>(ws + OFF_BSC)[(((l * 4 + b) * 16 + n) << 1) | t]
            = SCALE * bb[b * 32 + 2 * n + t];
    } else if (i < 12544) {
        // W0f[b][t][n][k]: quad q = k>>3, jj = k&7.
        //   q==0, jj<3 : Wh row jj      (pairs with xh -> xh*Wh)
        //   q==0, 3<=jj<6 : Wh row jj-3 (pairs with xl -> xl*Wh)
        //   q==1, jj<3 : Wl row jj      (pairs with xh -> xh*Wl)
        //   else 0
        int j = i - 8448;
        int k = j & 31, n = (j >> 5) & 15, t = (j >> 9) & 1, b = (j >> 10) & 3;
        int f = 2 * n + t;
        int q = k >> 3, jj = k & 7;
        int row = -1; bool lo = false;
        if (q == 0 && jj < 6)      row = (jj < 3) ? jj : jj - 3;
        else if (q == 1 && jj < 3) { row = jj; lo = true; }
        f16 outv = (f16)0.0f;
        if (row >= 0) {
            float w  = SCALE * W0[(b * 3 + row) * 32 + f];
            f16   wh = (f16)w;
            outv = lo ? (f16)(w - (float)wh) : wh;
        }
        reinterpret_cast<f16*>(ws + OFF_W0F)[((b * 2 + t) * 16 + n) * 32 + k] = outv;
    } else if (i < 12672) {
        // B0p pairs: [b*16+n] -> (bias_even, bias_odd)
        int j = i - 12544;
        int n = j & 15, t = (j >> 4) & 1, b = j >> 5;
        reinterpret_cast<float*>(ws + OFF_B0P)[(((b) * 16 + n) << 1) | t]
            = SCALE * b0[b * 32 + 2 * n + t];
    } else if (i < 12736) {
        int j = i - 12672;              // j = b*16 + pair
        union { hfx2 h; unsigned int u; } cv;
        cv.h = __builtin_amdgcn_cvt_pkrtz(-2.0f * W3[2 * j], -2.0f * W3[2 * j + 1]);
        reinterpret_cast<unsigned int*>(ws + OFF_W3P)[j] = cv.u;
    }
}

__global__ __launch_bounds__(BLOCK, 8) void pfnn_kernel(
    const float* __restrict__ x, const unsigned char* __restrict__ ws,
    const float* __restrict__ b3,
    float* __restrict__ out)
{
    __shared__ __align__(16) unsigned char Hl[4][64 * HROW]; // per-wave h tile

    const f16*   Wf  = reinterpret_cast<const f16*>(ws);
    const float* Bsc = reinterpret_cast<const float*>(ws + OFF_BSC);
    const f16*   W0f = reinterpret_cast<const f16*>(ws + OFF_W0F);
    const float* B0p = reinterpret_cast<const float*>(ws + OFF_B0P);
    const unsigned int* W3p = reinterpret_cast<const unsigned int*>(ws + OFF_W3P);

    const int t    = threadIdx.x;
    const int lane = t & 63;
    const int wv   = t >> 6;
    const int col  = lane & 15;
    const int quad = lane >> 4;
    unsigned char* __restrict__ H = &Hl[wv][0];

    const int n0 = blockIdx.x * BLOCK + t;
    const float x0 = x[3 * n0 + 0];
    const float x1 = x[3 * n0 + 1];
    const float x2 = x[3 * n0 + 2];

    // ---- build L0 A-frags once: hi/lo f16 split of x, gathered per m-tile ----
    // d0=(xh0,xh1) d1=(xh2,xl0) d2=(xl1,xl2); frag = [d0,d1,d2,0] for ALL quads.
    f16x8 xfrag[4];
    {
        union { hfx2 h; int u; } q0_, q1_, q2_;
        q0_.h = __builtin_amdgcn_cvt_pkrtz(x0, x1);          // RTZ hi parts
        float r0 = x0 - (float)q0_.h[0];
        float r1 = x1 - (float)q0_.h[1];
        q1_.h = __builtin_amdgcn_cvt_pkrtz(x2, r0);
        float r2 = x2 - (float)q1_.h[0];
        q2_.h = __builtin_amdgcn_cvt_pkrtz(r1, r2);
        int d0 = q0_.u, d1 = q1_.u, d2 = q2_.u;
        #pragma unroll
        for (int mt = 0; mt < 4; ++mt) {
            int addr = 4 * (mt * 16 + col);                  // byte addr = lane*4
            union { int i[4]; f16x8 f; } u;
            u.i[0] = __builtin_amdgcn_ds_bpermute(addr, d0);
            u.i[1] = __builtin_amdgcn_ds_bpermute(addr, d1);
            u.i[2] = __builtin_amdgcn_ds_bpermute(addr, d2);
            u.i[3] = 0;
            xfrag[mt] = u.f;
        }
    }

    float res[4];
    const unsigned char* __restrict__ row = H + lane * HROW;

    #pragma unroll 1
    for (int b = 0; b < 4; ++b) {
        layer0_block(b, xfrag, W0f, B0p, H, col, quad);
        hidden_block(0, b, Wf, Bsc, H, col, quad);
        hidden_block(1, b, Wf, Bsc, H, col, quad);

        // ---------- layer 3: 32 -> 1 (weights pre-multiplied by -2) ----------
        uint4 u0 = *reinterpret_cast<const uint4*>(row);
        uint4 u1 = *reinterpret_cast<const uint4*>(row + 16);
        uint4 u2 = *reinterpret_cast<const uint4*>(row + 32);
        uint4 u3 = *reinterpret_cast<const uint4*>(row + 48);
        const uint4* wv4 = reinterpret_cast<const uint4*>(W3p + b * 16);
        uint4 w0 = wv4[0], w1 = wv4[1], w2 = wv4[2], w3v = wv4[3];
        float a0 = dot8(u0.x, u0.y, u0.z, u0.w, w0, b3[b]);
        float a1 = dot8(u1.x, u1.y, u1.z, u1.w, w1, 0.0f);
        float a2 = dot8(u2.x, u2.y, u2.z, u2.w, w2, 0.0f);
        float a3 = dot8(u3.x, u3.y, u3.z, u3.w, w3v, 0.0f);
        res[b] = (a0 + a1) + (a2 + a3);
    }

    float4 r4 = make_float4(res[0], res[1], res[2], res[3]);
    *reinterpret_cast<float4*>(out + 4 * n0) = r4;
}

extern "C" void kernel_launch(void* const* d_in, const int* in_sizes, int n_in,
                              void* d_out, int out_size, void* d_ws, size_t ws_size,
                              hipStream_t stream) {
    const float* x  = (const float*)d_in[0];
    const float* W0 = (const float*)d_in[1];
    const float* b0 = (const float*)d_in[2];
    const float* W1 = (const float*)d_in[3];
    const float* b1 = (const float*)d_in[4];
    const float* W2 = (const float*)d_in[5];
    const float* b2 = (const float*)d_in[6];
    const float* W3 = (const float*)d_in[7];
    const float* b3 = (const float*)d_in[8];
    float* out = (float*)d_out;
    unsigned char* ws = (unsigned char*)d_ws;

    prep_kernel<<<dim3(50), dim3(256), 0, stream>>>(W0, b0, W1, b1, W2, b2, W3, ws);
    pfnn_kernel<<<dim3(NPTS / BLOCK), dim3(BLOCK), 0, stream>>>(x, ws, b3, out);
}